// Round 1
// baseline (208.909 us; speedup 1.0000x reference)
//
#include <hip/hip_runtime.h>
#include <math.h>

#define N 512
#define C 157
#define M 20
#define NW 8   // waves per block (512 threads)

// loss = -(sum of per-element log terms) / (N*C*3)
#define LOSS_SCALE (-1.0f / ((float)N * (float)C * 3.0f))

__device__ __forceinline__ float sigmoidf_(float x) {
    return 1.0f / (1.0f + __expf(-x));
}

// out[N*C] accumulator must be zeroed before atf_main_kernel's atomicAdds.
__global__ void atf_zero_kernel(float* __restrict__ out) {
    out[N * C] = 0.0f;
}

__global__ __launch_bounds__(512, 4) void atf_main_kernel(
    const float* __restrict__ a,
    const float* __restrict__ aa,
    const float* __restrict__ target,
    const float* __restrict__ bank_values,
    const int* __restrict__ bank_times,
    const int* __restrict__ bank_mask,   // jax bool -> harness int32
    const int* __restrict__ ids,
    const int* __restrict__ times,
    float* __restrict__ out)             // qa [N*C] + loss at out[N*C]
{
    const int n    = blockIdx.x;
    const int tid  = threadIdx.x;
    const int wave = tid >> 6;
    const int lane = tid & 63;

    __shared__ float s_ts[M];
    __shared__ int   s_mk[M];
    __shared__ float s_msg[C];
    __shared__ float s_fmsg[C];
    __shared__ float s_rowp[8][C];      // stride 157 mod 32 = 29 -> conflict-free
    __shared__ float s_colp[NW][C];
    __shared__ float s_red[NW];

    const int   id = ids[n];
    const float t0 = (float)times[n];

    const float* aan = aa + (size_t)n * C * C;
    const int j0 = lane, j1 = lane + 64, j2 = lane + 128;
    const bool ok1 = (j1 < C), ok2 = (j2 < C);

    // ---- issue bank_times/mask -> LDS (oldest vmem ops) ----
    if (tid < M) {
        s_ts[tid] = (float)bank_times[(size_t)id * M + tid];
        s_mk[tid] = (bank_mask[(size_t)id * M + tid] != 0) ? 1 : 0;
    }

    // ---- issue phase-1 gather + epilogue inputs into registers ----
    float av = 0.0f, tv = 0.0f;
    float vv[M];
    if (tid < C) {
        av = a[(size_t)n * C + tid];
        tv = target[(size_t)n * C + tid];
        const float* vb = bank_values + (size_t)id * M * C + tid;
        #pragma unroll
        for (int m = 0; m < M; ++m) vv[m] = vb[(size_t)m * C];
    }

    // ---- issue aa group A (row pairs 0..4, rows wave+16p / wave+16p+8) ----
    // These 30 loads/lane stay in flight across the lgkm-only barriers below:
    // the aa stream overlaps the msg/fmsg computation.
    float rA[5][3], rB[5][3];
    #pragma unroll
    for (int p = 0; p < 5; ++p) {
        const float* rowA = aan + (wave + p * 16) * C;
        rA[p][0] = rowA[j0];
        rA[p][1] = ok1 ? rowA[j1] : 0.0f;
        rA[p][2] = ok2 ? rowA[j2] : 0.0f;
        const float* rowB = aan + (wave + p * 16 + 8) * C;
        rB[p][0] = rowB[j0];
        rB[p][1] = ok1 ? rowB[j1] : 0.0f;
        rB[p][2] = ok2 ? rowB[j2] : 0.0f;
    }

    // barrier #1: s_ts/s_mk visible. LDS-only drain — do NOT drain vmcnt,
    // the aa group-A loads must stay in flight (counted-vmcnt discipline).
    asm volatile("s_waitcnt lgkmcnt(0)" ::: "memory");
    __builtin_amdgcn_s_barrier();

    // ---- phase 1: msg / fmsg (cond is block-uniform: no divergence) ----
    if (tid < C) {
        const float inv2s2 = 1.0f / (2.0f * 300.0f * 300.0f);
        const float INVDEC = 1.0f / 0.9f;
        float accP = 0.f, accF = 0.f, denP = 0.f, denF = 0.f;
        float wP = 1.f, wF = 1.f;
        #pragma unroll
        for (int m = 0; m < M; ++m) {
            const float ts = s_ts[m];
            const float d  = ts - t0;
            const float kern = __expf(-d * d * inv2s2);
            const float v = vv[m];
            const bool mk = (s_mk[m] != 0);
            if (mk && ts < t0) { accP += wP * kern * v; denP += wP; wP *= INVDEC; }
            if (mk && ts > t0) { accF += wF * kern * v; denF += wF; wF *= INVDEC; }
        }
        s_msg[tid]  = (denP > 0.f) ? accP / fmaxf(denP, 1e-7f) : 0.0f;
        s_fmsg[tid] = (denF > 0.f) ? accF / fmaxf(denF, 1e-7f) : 0.0f;
    }

    // barrier #2: s_msg/s_fmsg visible. Group-A aa loads still in flight.
    asm volatile("s_waitcnt lgkmcnt(0)" ::: "memory");
    __builtin_amdgcn_s_barrier();

    // ---- issue aa group B (row pairs 5..9); arrives under group-A compute ----
    float rA2[5][3], rB2[5][3];
    #pragma unroll
    for (int p = 0; p < 5; ++p) {
        const int iA = wave + (p + 5) * 16;
        const int iB = iA + 8;
        const float* rowA = aan + iA * C;
        rA2[p][0] = rowA[j0];
        rA2[p][1] = ok1 ? rowA[j1] : 0.0f;
        rA2[p][2] = ok2 ? rowA[j2] : 0.0f;
        if (iB < C) {
            const float* rowB = aan + iB * C;
            rB2[p][0] = rowB[j0];
            rB2[p][1] = ok1 ? rowB[j1] : 0.0f;
            rB2[p][2] = ok2 ? rowB[j2] : 0.0f;
        } else {
            rB2[p][0] = 0.0f; rB2[p][1] = 0.0f; rB2[p][2] = 0.0f;
        }
    }

    const float f0 = s_fmsg[j0];
    const float f1 = ok1 ? s_fmsg[j1] : 0.0f;
    const float f2 = ok2 ? s_fmsg[j2] : 0.0f;
    float col0 = 0.f, col1 = 0.f, col2 = 0.f;

    // ---- compute group A ----
    #pragma unroll
    for (int p = 0; p < 5; ++p) {
        const int iA = wave + p * 16;
        const int iB = iA + 8;
        const float mA = s_msg[iA];
        const float mB = s_msg[iB];
        col0 += rA[p][0] * mA + rB[p][0] * mB;
        col1 += rA[p][1] * mA + rB[p][1] * mB;
        col2 += rA[p][2] * mA + rB[p][2] * mB;
        float rpA = rA[p][0] * f0 + rA[p][1] * f1 + rA[p][2] * f2;
        float rpB = rB[p][0] * f0 + rB[p][1] * f1 + rB[p][2] * f2;
        rpA += __shfl_down(rpA, 32, 64);  rpB += __shfl_down(rpB, 32, 64);
        rpA += __shfl_down(rpA, 16, 64);  rpB += __shfl_down(rpB, 16, 64);
        rpA += __shfl_down(rpA,  8, 64);  rpB += __shfl_down(rpB,  8, 64);
        if (lane < 8) {
            s_rowp[lane][iA] = rpA;
            s_rowp[lane][iB] = rpB;
        }
    }
    // ---- compute group B ----
    #pragma unroll
    for (int p = 0; p < 5; ++p) {
        const int iA = wave + (p + 5) * 16;
        const int iB = iA + 8;
        const bool okB = (iB < C);
        const float mA = s_msg[iA];
        const float mB = okB ? s_msg[iB] : 0.0f;
        col0 += rA2[p][0] * mA + rB2[p][0] * mB;
        col1 += rA2[p][1] * mA + rB2[p][1] * mB;
        col2 += rA2[p][2] * mA + rB2[p][2] * mB;
        float rpA = rA2[p][0] * f0 + rA2[p][1] * f1 + rA2[p][2] * f2;
        float rpB = rB2[p][0] * f0 + rB2[p][1] * f1 + rB2[p][2] * f2;
        rpA += __shfl_down(rpA, 32, 64);  rpB += __shfl_down(rpB, 32, 64);
        rpA += __shfl_down(rpA, 16, 64);  rpB += __shfl_down(rpB, 16, 64);
        rpA += __shfl_down(rpA,  8, 64);  rpB += __shfl_down(rpB,  8, 64);
        if (lane < 8) {
            s_rowp[lane][iA] = rpA;
            if (okB) s_rowp[lane][iB] = rpB;
        }
    }

    s_colp[wave][j0] = col0;
    if (ok1) s_colp[wave][j1] = col1;
    if (ok2) s_colp[wave][j2] = col2;
    __syncthreads();   // full drain fine: all global loads consumed

    // ---- epilogue ----
    float local = 0.0f;
    if (tid < C) {
        float colsum = 0.0f;
        #pragma unroll
        for (int w = 0; w < NW; ++w) colsum += s_colp[w][tid];
        float rowsum = 0.0f;
        #pragma unroll
        for (int k = 0; k < 8; ++k) rowsum += s_rowp[k][tid];

        const float qlin = av + colsum + rowsum;
        const float p = sigmoidf_(qlin);
        out[(size_t)n * C + tid] = p;

        float pc = fminf(fmaxf(p, 1e-7f), 1.0f - 1e-7f);
        float pa = sigmoidf_(av);
        pa = fminf(fmaxf(pa, 1e-7f), 1.0f - 1e-7f);
        local = tv * logf(pc) + (1.0f - tv) * logf(1.0f - pc)
              + tv * logf(pa) + (1.0f - tv) * logf(1.0f - pa);
    }
    #pragma unroll
    for (int off = 32; off > 0; off >>= 1) local += __shfl_down(local, off, 64);
    if (lane == 0) s_red[wave] = local;
    __syncthreads();
    if (tid == 0) {
        float s = 0.0f;
        #pragma unroll
        for (int w = 0; w < NW; ++w) s += s_red[w];
        // device-scope atomic; ordering vs atf_zero_kernel guaranteed by stream order
        atomicAdd(out + N * C, s * LOSS_SCALE);
    }
}

extern "C" void kernel_launch(void* const* d_in, const int* in_sizes, int n_in,
                              void* d_out, int out_size, void* d_ws, size_t ws_size,
                              hipStream_t stream) {
    const float* a           = (const float*)d_in[0];
    const float* aa          = (const float*)d_in[1];
    const float* target      = (const float*)d_in[2];
    const float* bank_values = (const float*)d_in[3];
    const int*   bank_times  = (const int*)d_in[4];
    const int*   bank_mask   = (const int*)d_in[5];
    const int*   ids         = (const int*)d_in[6];
    const int*   times       = (const int*)d_in[7];

    float* out = (float*)d_out;

    atf_zero_kernel<<<1, 1, 0, stream>>>(out);
    atf_main_kernel<<<N, 512, 0, stream>>>(a, aa, target, bank_values, bank_times,
                                           bank_mask, ids, times, out);
}

// Round 2
// 203.699 us; speedup vs baseline: 1.0256x; 1.0256x over previous
//
#include <hip/hip_runtime.h>
#include <math.h>

#define N 512
#define C 157
#define M 20
#define NW 8   // waves per block (512 threads)

__device__ __forceinline__ float sigmoidf_(float x) {
    return 1.0f / (1.0f + __expf(-x));
}

__global__ __launch_bounds__(512, 4) void atf_main_kernel(
    const float* __restrict__ a,
    const float* __restrict__ aa,
    const float* __restrict__ target,
    const float* __restrict__ bank_values,
    const int* __restrict__ bank_times,
    const int* __restrict__ bank_mask,   // jax bool -> harness int32
    const int* __restrict__ ids,
    const int* __restrict__ times,
    float* __restrict__ out,             // qa [N*C]
    float* __restrict__ loss_part)       // [N] partial sums of log terms
{
    const int n    = blockIdx.x;
    const int tid  = threadIdx.x;
    const int wave = tid >> 6;
    const int lane = tid & 63;

    __shared__ float s_ts[M];
    __shared__ int   s_mk[M];
    __shared__ float s_msg[C];
    __shared__ float s_fmsg[C];
    __shared__ float s_rowp[8][C];      // stride 157 mod 32 = 29 -> conflict-free
    __shared__ float s_colp[NW][C];
    __shared__ float s_red[NW];

    const int   id = ids[n];
    const float t0 = (float)times[n];

    const float* aan = aa + (size_t)n * C * C;
    const int j0 = lane, j1 = lane + 64, j2 = lane + 128;
    const bool ok1 = (j1 < C), ok2 = (j2 < C);

    // ---- issue bank_times/mask -> LDS ----
    if (tid < M) {
        s_ts[tid] = (float)bank_times[(size_t)id * M + tid];
        s_mk[tid] = (bank_mask[(size_t)id * M + tid] != 0) ? 1 : 0;
    }

    // ---- issue phase-1 gather + epilogue inputs into registers ----
    float av = 0.0f, tv = 0.0f;
    float vv[M];
    if (tid < C) {
        av = a[(size_t)n * C + tid];
        tv = target[(size_t)n * C + tid];
        const float* vb = bank_values + (size_t)id * M * C + tid;
        #pragma unroll
        for (int m = 0; m < M; ++m) vv[m] = vb[(size_t)m * C];
    }

    // ---- prefetch first 3 row-pairs (pairs p: rows wave+16p, wave+16p+8) ----
    // 18 regs in flight; stays in flight across the lgkm-only barriers below.
    float buf[3][6];
    #pragma unroll
    for (int p = 0; p < 3; ++p) {
        const float* rowA = aan + (wave + p * 16) * C;
        buf[p][0] = rowA[j0];
        buf[p][1] = ok1 ? rowA[j1] : 0.0f;
        buf[p][2] = ok2 ? rowA[j2] : 0.0f;
        const float* rowB = aan + (wave + p * 16 + 8) * C;
        buf[p][3] = rowB[j0];
        buf[p][4] = ok1 ? rowB[j1] : 0.0f;
        buf[p][5] = ok2 ? rowB[j2] : 0.0f;
    }

    // barrier #1: s_ts/s_mk visible. LDS-only drain — global loads stay in flight.
    asm volatile("s_waitcnt lgkmcnt(0)" ::: "memory");
    __builtin_amdgcn_s_barrier();

    // ---- phase 1: msg / fmsg (conditions are per-m uniform across block) ----
    if (tid < C) {
        const float inv2s2 = 1.0f / (2.0f * 300.0f * 300.0f);
        const float INVDEC = 1.0f / 0.9f;
        float accP = 0.f, accF = 0.f, denP = 0.f, denF = 0.f;
        float wP = 1.f, wF = 1.f;
        #pragma unroll
        for (int m = 0; m < M; ++m) {
            const float ts = s_ts[m];
            const float d  = ts - t0;
            const float kern = __expf(-d * d * inv2s2);
            const float v = vv[m];
            const bool mk = (s_mk[m] != 0);
            if (mk && ts < t0) { accP += wP * kern * v; denP += wP; wP *= INVDEC; }
            if (mk && ts > t0) { accF += wF * kern * v; denF += wF; wF *= INVDEC; }
        }
        s_msg[tid]  = (denP > 0.f) ? accP / fmaxf(denP, 1e-7f) : 0.0f;
        s_fmsg[tid] = (denF > 0.f) ? accF / fmaxf(denF, 1e-7f) : 0.0f;
    }

    // barrier #2: s_msg/s_fmsg visible. aa prefetches still in flight.
    asm volatile("s_waitcnt lgkmcnt(0)" ::: "memory");
    __builtin_amdgcn_s_barrier();

    const float f0 = s_fmsg[j0];
    const float f1 = ok1 ? s_fmsg[j1] : 0.0f;
    const float f2 = ok2 ? s_fmsg[j2] : 0.0f;
    float col0 = 0.f, col1 = 0.f, col2 = 0.f;

    // ---- phase 2: 3-deep software-pipelined pair loop (10 pairs) ----
    #pragma unroll
    for (int p = 0; p < 10; ++p) {
        const int slot = p % 3;            // compile-time under full unroll
        const int iA = wave + p * 16;
        const int iB = iA + 8;
        const bool okB = (iB < C);         // only pair 9 can fail (wave>=5)

        const float a0 = buf[slot][0], a1 = buf[slot][1], a2 = buf[slot][2];
        const float b0 = buf[slot][3], b1 = buf[slot][4], b2 = buf[slot][5];

        const float mA = s_msg[iA];
        const float mB = okB ? s_msg[iB] : 0.0f;

        col0 += a0 * mA + b0 * mB;
        col1 += a1 * mA + b1 * mB;
        col2 += a2 * mA + b2 * mB;

        float rpA = a0 * f0 + a1 * f1 + a2 * f2;
        float rpB = b0 * f0 + b1 * f1 + b2 * f2;
        rpA += __shfl_down(rpA, 32, 64);  rpB += __shfl_down(rpB, 32, 64);
        rpA += __shfl_down(rpA, 16, 64);  rpB += __shfl_down(rpB, 16, 64);
        rpA += __shfl_down(rpA,  8, 64);  rpB += __shfl_down(rpB,  8, 64);
        if (lane < 8) {
            s_rowp[lane][iA] = rpA;
            if (okB) s_rowp[lane][iB] = rpB;
        }

        // refill the freed slot with pair p+3
        if (p + 3 < 10) {
            const int q = p + 3;
            const float* rowA = aan + (wave + q * 16) * C;
            buf[slot][0] = rowA[j0];
            buf[slot][1] = ok1 ? rowA[j1] : 0.0f;
            buf[slot][2] = ok2 ? rowA[j2] : 0.0f;
            const int ibq = wave + q * 16 + 8;
            if (ibq < C) {
                const float* rowB = aan + ibq * C;
                buf[slot][3] = rowB[j0];
                buf[slot][4] = ok1 ? rowB[j1] : 0.0f;
                buf[slot][5] = ok2 ? rowB[j2] : 0.0f;
            } else {
                buf[slot][3] = 0.0f; buf[slot][4] = 0.0f; buf[slot][5] = 0.0f;
            }
        }
    }

    s_colp[wave][j0] = col0;
    if (ok1) s_colp[wave][j1] = col1;
    if (ok2) s_colp[wave][j2] = col2;
    __syncthreads();   // full drain fine: all global loads consumed

    // ---- epilogue ----
    float local = 0.0f;
    if (tid < C) {
        float colsum = 0.0f;
        #pragma unroll
        for (int w = 0; w < NW; ++w) colsum += s_colp[w][tid];
        float rowsum = 0.0f;
        #pragma unroll
        for (int k = 0; k < 8; ++k) rowsum += s_rowp[k][tid];

        const float qlin = av + colsum + rowsum;
        const float p = sigmoidf_(qlin);
        out[(size_t)n * C + tid] = p;

        float pc = fminf(fmaxf(p, 1e-7f), 1.0f - 1e-7f);
        float pa = sigmoidf_(av);
        pa = fminf(fmaxf(pa, 1e-7f), 1.0f - 1e-7f);
        // __logf: fast-math log; loss tolerance (absmax 3.9e-3) is far above
        // the ~1e-6 relative error this introduces in an averaged scalar.
        local = tv * __logf(pc) + (1.0f - tv) * __logf(1.0f - pc)
              + tv * __logf(pa) + (1.0f - tv) * __logf(1.0f - pa);
    }
    #pragma unroll
    for (int off = 32; off > 0; off >>= 1) local += __shfl_down(local, off, 64);
    if (lane == 0) s_red[wave] = local;
    __syncthreads();
    if (tid == 0) {
        float s = 0.0f;
        #pragma unroll
        for (int w = 0; w < NW; ++w) s += s_red[w];
        loss_part[n] = s;
    }
}

__global__ __launch_bounds__(256) void atf_finalize_kernel(
    const float* __restrict__ loss_part,
    float* __restrict__ out)
{
    const int tid  = threadIdx.x;
    const int wave = tid >> 6;
    const int lane = tid & 63;
    __shared__ double s_red[4];

    double local = (double)loss_part[tid] + (double)loss_part[tid + 256];
    #pragma unroll
    for (int off = 32; off > 0; off >>= 1) local += __shfl_down(local, off, 64);
    if (lane == 0) s_red[wave] = local;
    __syncthreads();
    if (tid == 0) {
        const double s = s_red[0] + s_red[1] + s_red[2] + s_red[3];
        out[N * C] = (float)(-s / ((double)(N * C) * 3.0));
    }
}

extern "C" void kernel_launch(void* const* d_in, const int* in_sizes, int n_in,
                              void* d_out, int out_size, void* d_ws, size_t ws_size,
                              hipStream_t stream) {
    const float* a           = (const float*)d_in[0];
    const float* aa          = (const float*)d_in[1];
    const float* target      = (const float*)d_in[2];
    const float* bank_values = (const float*)d_in[3];
    const int*   bank_times  = (const int*)d_in[4];
    const int*   bank_mask   = (const int*)d_in[5];
    const int*   ids         = (const int*)d_in[6];
    const int*   times       = (const int*)d_in[7];

    float* out       = (float*)d_out;
    float* loss_part = (float*)d_ws;   // 512 floats

    atf_main_kernel<<<N, 512, 0, stream>>>(a, aa, target, bank_values, bank_times,
                                           bank_mask, ids, times, out, loss_part);
    atf_finalize_kernel<<<1, 256, 0, stream>>>(loss_part, out);
}